// Round 6
// baseline (953.233 us; speedup 1.0000x reference)
//
#include <hip/hip_runtime.h>
#include <hip/hip_bf16.h>

#define NT_ 10000
#define B_  128
#define S_  500

typedef _Float16 h2_t __attribute__((ext_vector_type(2)));
typedef unsigned int uint32;

__device__ __forceinline__ uint32 pack2(float a, float b) {
    return __builtin_bit_cast(uint32, __builtin_amdgcn_cvt_pkrtz(a, b));
}
__device__ __forceinline__ float dot2(uint32 w, uint32 h, float acc) {
#if __has_builtin(__builtin_amdgcn_fdot2)
    return __builtin_amdgcn_fdot2(__builtin_bit_cast(h2_t, w),
                                  __builtin_bit_cast(h2_t, h), acc, false);
#else
    h2_t wv = __builtin_bit_cast(h2_t, w), hv = __builtin_bit_cast(h2_t, h);
    acc = fmaf((float)wv[0], (float)hv[0], acc);
    return fmaf((float)wv[1], (float)hv[1], acc);
#endif
}

// ---------------------------------------------------------------------------
// Kernel A: per-topic precompute (blockIdx.y = 0: topicAct, 1: topicGate)
// ---------------------------------------------------------------------------
__global__ __launch_bounds__(128) void prep_topic(
    const float* __restrict__ emb_topic,
    const float* __restrict__ emb_resps,
    const float* __restrict__ W_in,
    const float* __restrict__ W_gate,
    float* __restrict__ topicAct,
    float* __restrict__ topicGate,
    float* __restrict__ respAct)
{
    const int u    = threadIdx.x;
    const int blk  = blockIdx.x;
    const int mode = blockIdx.y;
    __shared__ float e[8][128];

    if (blk == NT_ / 8) {
        if (mode) return;
        e[0][u] = emb_resps[u];
        e[1][u] = emb_resps[128 + u];
        __syncthreads();
        float a0 = 0.f, a1 = 0.f;
        for (int k = 0; k < 128; ++k) {
            float wv = W_in[(128 + k) * 128 + u];
            a0 += e[0][k] * wv;
            a1 += e[1][k] * wv;
        }
        respAct[u]       = a0;
        respAct[128 + u] = a1;
        return;
    }

    const int t0 = blk * 8;
    #pragma unroll
    for (int j = 0; j < 8; ++j) e[j][u] = emb_topic[(t0 + j) * 128 + u];
    __syncthreads();

    const float* __restrict__ W = mode ? (W_gate + 256 * 128) : W_in;
    float acc[8];
    #pragma unroll
    for (int j = 0; j < 8; ++j) acc[j] = 0.f;
    for (int k = 0; k < 128; ++k) {
        float wv = W[k * 128 + u];
        #pragma unroll
        for (int j = 0; j < 8; ++j) acc[j] += e[j][k] * wv;
    }
    float* __restrict__ dst = mode ? topicGate : topicAct;
    #pragma unroll
    for (int j = 0; j < 8; ++j) dst[(t0 + j) * 128 + u] = acc[j];
}

// ---------------------------------------------------------------------------
// Kernel B: per-(topic,resp) streams (blockIdx.y = mat 0..3)
// ---------------------------------------------------------------------------
__global__ __launch_bounds__(128) void prep_streams(
    const float* __restrict__ topicAct,
    const float* __restrict__ topicGate,
    const float* __restrict__ respAct,
    const float* __restrict__ b_in,
    const float* __restrict__ W_time,
    const float* __restrict__ W_att,
    const float* __restrict__ W_hint,
    const float* __restrict__ W_gate,
    float* __restrict__ streams)
{
    const int u   = threadIdx.x;
    const int t0  = blockIdx.x * 8;
    const int mat = blockIdx.y;
    __shared__ float a_lds[16][128];

    const float bi = b_in[u];
    const float r0 = respAct[u];
    const float r1 = respAct[128 + u];
    #pragma unroll
    for (int j = 0; j < 8; ++j) {
        float ta = topicAct[(t0 + j) * 128 + u];
        a_lds[j * 2 + 0][u] = fmaxf(ta + r0 + bi, 0.f);
        a_lds[j * 2 + 1][u] = fmaxf(ta + r1 + bi, 0.f);
    }
    __syncthreads();

    const float* __restrict__ Wp =
        (mat == 0 ? W_time + 128 : mat == 1 ? W_att + 128 :
         mat == 2 ? W_hint + 128 : W_gate + 128 * 128) + u;

    float acc[16];
    #pragma unroll
    for (int r = 0; r < 16; ++r) acc[r] = 0.f;
    for (int k = 0; k < 128; ++k) {
        float wv = Wp[(size_t)k * 128];
        #pragma unroll
        for (int r = 0; r < 16; ++r) acc[r] += a_lds[r][k] * wv;
    }
    #pragma unroll
    for (int r = 0; r < 16; ++r) {
        float v = acc[r];
        int   t = t0 + (r >> 1);
        if (mat == 3) v += topicGate[t * 128 + u];
        streams[((size_t)t * 2 + (r & 1)) * 512 + mat * 128 + u] = v;
    }
}

// ---------------------------------------------------------------------------
// Kernel C: 500-step recurrence. 1 block/row, 1024 threads = 128 u x 8 roles.
// 16 waves -> 4 waves/SIMD (2x the latency-hiding of the 512-thread version).
//   r0: W_out (sig)      r1: W_gate (gamma)   r2: W_time (gt)
//   r4: W_att (ga)       r6: W_hint (gh)      r3/r5/r7: spare (dup W_out)
// Each z is a FULL k=128 dot in-lane -> zero shfls for all five z's.
// H m-split over r>>1 (8 m's/lane, dup x2). lg: 3 shfl_xor; gamma: 1 bcast.
// cap precomputed per step in LDS preload. One LDS-only barrier/step.
// ---------------------------------------------------------------------------
__device__ __forceinline__ float sigmoidf_(float x) {
    return 1.f / (1.f + __expf(-x));
}
__device__ __forceinline__ float tanhf_(float x) {
    float e = __expf(2.f * x);
    return 1.f - 2.f / (e + 1.f);
}

#define LDS_BARRIER()                                         \
    do {                                                      \
        asm volatile("s_waitcnt lgkmcnt(0)" ::: "memory");    \
        __builtin_amdgcn_s_barrier();                         \
        asm volatile("" ::: "memory");                        \
    } while (0)

__global__ __launch_bounds__(1024)
void recurrent(
    const int*   __restrict__ topics, const int* __restrict__ resps,
    const float* __restrict__ tf_, const float* __restrict__ af_,
    const float* __restrict__ hf_, const int* __restrict__ masks,
    const float* __restrict__ q_matrix, const float* __restrict__ init_h,
    const float* __restrict__ W_out,  const float* __restrict__ b_out,
    const float* __restrict__ W_time, const float* __restrict__ b_time,
    const float* __restrict__ W_att,  const float* __restrict__ b_att,
    const float* __restrict__ W_hint, const float* __restrict__ b_hint,
    const float* __restrict__ W_cap,  const float* __restrict__ b_cap,
    const float* __restrict__ w_lg,
    const float* __restrict__ W_gate, const float* __restrict__ b_gate,
    const float* __restrict__ streams,
    float* __restrict__ out)
{
    const int tid  = threadIdx.x;
    const int u    = tid >> 3;      // 0..127
    const int r    = tid & 7;       // role
    const int lane = tid & 63;
    const int wv   = tid >> 6;      // wave 0..15
    const int b    = blockIdx.x;

    __shared__ int    sb_lds[S_];            // (topic*2+resp)*512
    __shared__ int    qb_lds[S_];            // topic*32
    __shared__ float4 sc_lds[S_];            // {tf, af, hf, mask}
    __shared__ float  cap_lds[S_];           // precomputed cap
    __shared__ float  w_lds[2][32];
    __shared__ __align__(16) uint32 ht_pk[2][64];
    __shared__ float  outbuf[8][2][128];     // [slot][which][u]

    const int base = b * S_;

    // ---- preload per-step data + precompute cap ----
    {
        const float wcv0 = W_cap[0], wcv1 = W_cap[1], wcv2 = W_cap[2],
                    wcv3 = W_cap[3], wcv4 = W_cap[4], wcv5 = W_cap[5],
                    wcv6 = W_cap[6], wcv7 = W_cap[7], bcv = b_cap[0];
        for (int i = tid; i < S_; i += 1024) {
            const int tpc = topics[base + i];
            const int rsp = resps [base + i];
            sb_lds[i] = (tpc * 2 + rsp) * 512;
            qb_lds[i] = tpc * 32;
            const float tf = tf_[base + i], af = af_[base + i], hf = hf_[base + i];
            sc_lds[i] = make_float4(tf, af, hf, masks[base + i] ? 1.f : 0.f);
            const float capin = wcv0*tf + wcv1*af + wcv2*hf + wcv3*(tf*af)
                              + wcv4*(tf*hf) + wcv5*(af*hf) + wcv6*(tf*af*hf)
                              + wcv7 + bcv;
            cap_lds[i] = 1.f / (1.f + __expf(-capin));
        }
    }

    // ---- f16-packed weights: own matrix full k=128 (64 u32 regs) ----
    const float* __restrict__ WpA =
        r == 0 ? W_out :
        r == 1 ? W_gate :
        r == 2 ? W_time + 129 * 128 :
        r == 4 ? W_att  + 129 * 128 :
        r == 6 ? W_hint + 129 * 128 : W_out;
    uint32 Wn[64];
    #pragma unroll
    for (int i = 0; i < 64; ++i)
        Wn[i] = pack2(WpA[(2 * i) * 128 + u], WpA[(2 * i + 1) * 128 + u]);
    #pragma unroll
    for (int i = 0; i < 16; ++i) {
        asm volatile("" : "+v"(Wn[4*i]), "+v"(Wn[4*i+1]),
                          "+v"(Wn[4*i+2]), "+v"(Wn[4*i+3]));
    }

    // H m-slice (r>>1)*8 .. +8 (dup across r&1)
    float H[8];
    #pragma unroll
    for (int j = 0; j < 8; ++j) H[j] = init_h[((r >> 1) * 8 + j) * 128 + u];

    // per-lane role constants
    const float cst_b  = (r == 0 ? b_out : r == 1 ? b_gate : r == 2 ? b_time :
                          r == 4 ? b_att : r == 6 ? b_hint : b_out)[u];
    const float cst_w0 = r == 2 ? W_time[u] : r == 4 ? W_att[u] :
                         r == 6 ? W_hint[u] : 0.f;
    const float wl_own = r == 2 ? w_lg[0] : r == 4 ? w_lg[1] :
                         r == 6 ? w_lg[2] : 0.f;
    const float svsel  = (r == 1 || r == 2 || r == 4 || r == 6) ? 1.f : 0.f;
    const int   svofs  = (r == 1 ? 384 : r == 2 ? 0 : r == 4 ? 128 :
                          r == 6 ? 256 : 0) + u;

    float* out_imp = out + B_ * (S_ - 1);

    __syncthreads();   // preload visible

    // ---- prime pipelines ----
    float sv_cur = streams[sb_lds[0] + svofs];
    float sv_nxt = streams[sb_lds[1] + svofs];
    float qv_cur = 0.f;
    if (tid < 32) {
        w_lds[0][tid] = q_matrix[qb_lds[0] + tid];
        qv_cur        = q_matrix[qb_lds[1] + tid];
    }
    __syncthreads();
    float4 wA = *(const float4*)&w_lds[0][(r >> 1) * 8];
    float4 wB = *(const float4*)&w_lds[0][(r >> 1) * 8 + 4];

    #pragma unroll 1
    for (int s = 0; s < S_; ++s) {
        const int buf = s & 1;

        // per-step scalars (broadcast LDS) + prefetch issue for s+2
        const float4 sc  = sc_lds[s];
        const float  cap = cap_lds[s];
        const float tf = sc.x, af = sc.y, hf = sc.z, msk = sc.w;
        const int s2 = (s + 2 < S_) ? s + 2 : S_ - 1;
        const float sv_new = streams[sb_lds[s2] + svofs];
        float qv_new = 0.f;
        if (tid < 32) qv_new = q_matrix[qb_lds[s2] + tid];

        // ---- h_tilde: 8-FMA partial + 2 chained shfl over m-slices ----
        float hp = wA.x * H[0] + wA.y * H[1] + wA.z * H[2] + wA.w * H[3]
                 + wB.x * H[4] + wB.y * H[5] + wB.z * H[6] + wB.w * H[7];
        hp += __shfl_xor(hp, 2);
        hp += __shfl_xor(hp, 4);
        const float hp2 = __shfl_down(hp, 8);          // ht of unit u+1
        if (r == 0 && !(u & 1)) ht_pk[buf][u >> 1] = pack2(hp, hp2);
        if (tid < 32) w_lds[buf ^ 1][tid] = qv_cur;    // w row for s+1
        LDS_BARRIER();

        // ---- deferred output flush: every 4 steps, 8 waves ----
        if ((s & 3) == 0 && s && wv < 8) {
            const int st = (s - 4) + (wv >> 1);
            const int which = wv & 1;
            const float2 p = *(const float2*)&outbuf[st & 7][which][2 * lane];
            float v = p.x + p.y;
            #pragma unroll
            for (int o = 1; o < 64; o <<= 1) v += __shfl_xor(v, o);
            if (lane == 0) {
                v *= (1.f / 128.f);
                if (which == 0) { if (st >= 1) out[b * (S_ - 1) + st - 1] = v; }
                else            out_imp[b * S_ + st] = v;
            }
        }

        const float4 wAn = *(const float4*)&w_lds[buf ^ 1][(r >> 1) * 8];
        const float4 wBn = *(const float4*)&w_lds[buf ^ 1][(r >> 1) * 8 + 4];

        // ---- own-matrix dot: full k=128 in-lane, NO cross-lane reduce ----
        const uint4* htb = (const uint4*)&ht_pk[buf][0];
        float x0 = 0, x1 = 0, x2 = 0, x3 = 0, x4 = 0, x5 = 0, x6 = 0, x7 = 0;
        #pragma unroll
        for (int c = 0; c < 16; c += 2) {
            const uint4 ha = htb[c], hb = htb[c + 1];
            x0 = dot2(Wn[c*4+0], ha.x, x0);
            x1 = dot2(Wn[c*4+1], ha.y, x1);
            x2 = dot2(Wn[c*4+2], ha.z, x2);
            x3 = dot2(Wn[c*4+3], ha.w, x3);
            x4 = dot2(Wn[c*4+4], hb.x, x4);
            x5 = dot2(Wn[c*4+5], hb.y, x5);
            x6 = dot2(Wn[c*4+6], hb.z, x6);
            x7 = dot2(Wn[c*4+7], hb.w, x7);
        }
        const float z = ((x0 + x4) + (x1 + x5)) + ((x2 + x6) + (x3 + x7));

        // ---- epilogue: roles in parallel lanes ----
        const float fac = r == 2 ? tf : r == 4 ? af : r == 6 ? hf : 0.f;
        const float arg = z + sv_cur * svsel + fac * cst_w0 + cst_b;
        const float th  = tanhf_(arg) * fac;           // r2/r4/r6
        float gs = wl_own * th;
        gs += __shfl_xor(gs, 2);
        gs += __shfl_xor(gs, 4);
        gs += __shfl_xor(gs, 1);                       // all 8 lanes: full sum
        const float lg  = cap * fmaxf(gs, 0.f);
        const float sgm = sigmoidf_(arg);              // r0: sig, r1: gamma
        const float gamma = __shfl(sgm, (lane & ~7) | 1);

        const float gme = 1.f + msk * (gamma - 1.f);
        const float lge = msk * lg;
        H[0] = fmaf(gme, H[0], wA.x * lge); H[1] = fmaf(gme, H[1], wA.y * lge);
        H[2] = fmaf(gme, H[2], wA.z * lge); H[3] = fmaf(gme, H[3], wA.w * lge);
        H[4] = fmaf(gme, H[4], wB.x * lge); H[5] = fmaf(gme, H[5], wB.y * lge);
        H[6] = fmaf(gme, H[6], wB.z * lge); H[7] = fmaf(gme, H[7], wB.w * lge);

        if (r == 0) {
            outbuf[s & 7][0][u] = msk * sgm;
            outbuf[s & 7][1][u] = lge;
        }

        // rotate pipelines
        wA = wAn; wB = wBn;
        sv_cur = sv_nxt; sv_nxt = sv_new; qv_cur = qv_new;
    }

    // ---- final flush: steps 496..499 ----
    __syncthreads();
    if (wv < 8) {
        const int st = 496 + (wv >> 1);
        const int which = wv & 1;
        const float2 p = *(const float2*)&outbuf[st & 7][which][2 * lane];
        float v = p.x + p.y;
        #pragma unroll
        for (int o = 1; o < 64; o <<= 1) v += __shfl_xor(v, o);
        if (lane == 0) {
            v *= (1.f / 128.f);
            if (which == 0) out[b * (S_ - 1) + st - 1] = v;
            else            out_imp[b * S_ + st] = v;
        }
    }
}

// ---------------------------------------------------------------------------
extern "C" void kernel_launch(void* const* d_in, const int* in_sizes, int n_in,
                              void* d_out, int out_size, void* d_ws, size_t ws_size,
                              hipStream_t stream)
{
    (void)in_sizes; (void)n_in; (void)out_size; (void)ws_size;

    const int*   topics    = (const int*)  d_in[0];
    const int*   resps     = (const int*)  d_in[1];
    const float* tf        = (const float*)d_in[2];
    const float* af        = (const float*)d_in[3];
    const float* hf        = (const float*)d_in[4];
    const int*   masks     = (const int*)  d_in[5];
    /* d_in[6] = training (ignored) */
    const float* emb_topic = (const float*)d_in[7];
    const float* emb_resps = (const float*)d_in[8];
    const float* q_matrix  = (const float*)d_in[9];
    const float* W_in      = (const float*)d_in[10];
    const float* b_in      = (const float*)d_in[11];
    const float* init_h    = (const float*)d_in[12];
    const float* W_out     = (const float*)d_in[13];
    const float* b_out     = (const float*)d_in[14];
    const float* W_time    = (const float*)d_in[15];
    const float* b_time    = (const float*)d_in[16];
    const float* W_att     = (const float*)d_in[17];
    const float* b_att     = (const float*)d_in[18];
    const float* W_hint    = (const float*)d_in[19];
    const float* b_hint    = (const float*)d_in[20];
    const float* W_cap     = (const float*)d_in[21];
    const float* b_cap     = (const float*)d_in[22];
    const float* w_lg      = (const float*)d_in[23];
    const float* W_gate    = (const float*)d_in[24];
    const float* b_gate    = (const float*)d_in[25];

    float* ws        = (float*)d_ws;
    float* topicAct  = ws;                         // 10000*128
    float* topicGate = topicAct + NT_ * 128;       // 10000*128
    float* respAct   = topicGate + NT_ * 128;      // 256
    float* streams   = respAct + 256;              // 10000*2*512

    prep_topic  <<<dim3(NT_ / 8 + 1, 2), 128, 0, stream>>>(
        emb_topic, emb_resps, W_in, W_gate, topicAct, topicGate, respAct);
    prep_streams<<<dim3(NT_ / 8, 4),     128, 0, stream>>>(
        topicAct, topicGate, respAct, b_in,
        W_time, W_att, W_hint, W_gate, streams);
    recurrent   <<<B_, 1024, 0, stream>>>(topics, resps, tf, af, hf, masks,
                                          q_matrix, init_h,
                                          W_out, b_out, W_time, b_time,
                                          W_att, b_att, W_hint, b_hint,
                                          W_cap, b_cap, w_lg, W_gate, b_gate,
                                          streams, (float*)d_out);
}